// Round 13
// baseline (554.596 us; speedup 1.0000x reference)
//
#include <hip/hip_runtime.h>
#include <hip/hip_bf16.h>
#include <cstdint>
#include <cstddef>

#define N_ROWS 8192
#define K_DIM  256
#define NP     5532
#define NC     10532
#define NCPAD  10752    // 84*128, zero-padded classes
#define IGN    5554
#define BM     256
#define BN     128
#define BK     32
#define CT     84             // NCPAD / BN
#define NRT    32             // N_ROWS / BM
#define NBLK   (CT * NRT)     // 2688 blocks, %8==0 -> bijective XCD swizzle
#define CPX    (NBLK / 8)     // 336

using f32x4  = __attribute__((ext_vector_type(4))) float;
using bf16x8 = __attribute__((ext_vector_type(8))) short;

__device__ __forceinline__ unsigned short f2bf(float f) {
    __hip_bfloat16 h = __float2bfloat16(f);
    return __builtin_bit_cast(unsigned short, h);
}

// One-shot f32 -> bf16 conversion. W = [lut;cq;pad] is PRE-SCALED by 30
// (bf16 relative error is scale-invariant), so GEMM acc = logit directly.
__global__ __launch_bounds__(256) void oim_convert(
    const float* __restrict__ X, const float* __restrict__ lut,
    const float* __restrict__ cq,
    unsigned short* __restrict__ Xb, unsigned short* __restrict__ Wb)
{
    const int XCH = (N_ROWS * K_DIM) / 8;   // 262144 chunks of 8 elems
    const int WCH = (NCPAD * K_DIM) / 8;    // 344064
    int c = blockIdx.x * 256 + threadIdx.x;
    if (c >= XCH + WCH) return;
    const float* src = nullptr;
    unsigned short* dst;
    float scale = 1.0f;
    if (c < XCH) {
        src = X + (size_t)c * 8;
        dst = Xb + (size_t)c * 8;
    } else {
        int wc  = c - XCH;
        int row = wc >> 5;          // 32 chunks per 256-elem row
        int off = (wc & 31) * 8;
        dst = Wb + (size_t)wc * 8;
        scale = 30.0f;
        if (row < NP)      src = lut + (size_t)row * K_DIM + off;
        else if (row < NC) src = cq + (size_t)(row - NP) * K_DIM + off;
    }
    ushort4 h0 = {0, 0, 0, 0}, h1 = {0, 0, 0, 0};
    if (src) {
        float4 v0 = *reinterpret_cast<const float4*>(src);
        float4 v1 = *reinterpret_cast<const float4*>(src + 4);
        h0.x = f2bf(v0.x * scale); h0.y = f2bf(v0.y * scale);
        h0.z = f2bf(v0.z * scale); h0.w = f2bf(v0.w * scale);
        h1.x = f2bf(v1.x * scale); h1.y = f2bf(v1.y * scale);
        h1.z = f2bf(v1.z * scale); h1.w = f2bf(v1.w * scale);
    }
    *reinterpret_cast<ushort4*>(dst)     = h0;
    *reinterpret_cast<ushort4*>(dst + 4) = h1;
}

// 256x128 bf16 GEMM, 512 threads (8 waves as 4 row x 2 col of 64x64).
// Same proven K-step discipline as R7/R12: per step {stage 24KB via
// global_load_lds w=16, __syncthreads, 16 MFMA/wave, __syncthreads}.
// Rationale: every 256-thread variant capped at ~12 resident waves/CU
// (~3 blocks); 8-wave blocks double waves/CU at the same block cap.
// LDS layout per operand (rows x 32 k): two rows per 128B line,
//   byte(r,g) = (r>>1)*128 + (r&1)*64 + ((g ^ ((r>>1)&3))<<4), g = k/8
// -> ds_read_b128 reads exactly 2-way bank-aliased (free). Source
// pre-permuted with inverse map r=((c>>3)<<1)|((c>>2)&1), g=(c&3)^((c>>3)&3).
__global__ __launch_bounds__(512, 8) void oim_gemm(
    const unsigned short* __restrict__ Xb, const unsigned short* __restrict__ Wb,
    const int* __restrict__ roi,
    float* __restrict__ partial, float* __restrict__ labelLogit)
{
    const int bid = blockIdx.x;
    const int L   = (bid & 7) * CPX + (bid >> 3);   // XCD-chunked, bijective
    const int ct  = L >> 5;                          // 0..83 (class tile)
    const int rt  = L & 31;                          // 0..31 (row tile)
    const int row0 = rt * BM;
    const int col0 = ct * BN;
    const int tid  = threadIdx.x;
    const int wave = tid >> 6;
    const int lane = tid & 63;
    const int wr   = wave >> 1;                      // 0..3 (row wave)
    const int wc   = wave & 1;                       // 0..1 (col wave)
    const int wm   = wr * 64;
    const int wn   = wc * 64;

    __shared__ __align__(16) unsigned short As[BM * BK];   // 16 KB
    __shared__ __align__(16) unsigned short Bs[BN * BK];   // 8 KB
    __shared__ int   lbl[BM];                               // 1 KB
    __shared__ float rs[BM][2];                             // 2 KB

    if (tid < BM) lbl[tid] = roi[row0 + tid] - 1;

    // Staging source pointers (pre-permuted). A: chunks c = i*512+tid
    // (i=0,1; 1024 chunks = 16KB). B: chunks c = tid (512 = 8KB).
    const unsigned short* aP[2];
    const unsigned short* bP0;
#pragma unroll
    for (int i = 0; i < 2; ++i) {
        int c = i * 512 + tid;
        int r = ((c >> 3) << 1) | ((c >> 2) & 1);
        int g = (c & 3) ^ ((c >> 3) & 3);
        aP[i] = Xb + (size_t)(row0 + r) * K_DIM + g * 8;
    }
    {
        int c = tid;
        int r = ((c >> 3) << 1) | ((c >> 2) & 1);
        int g = (c & 3) ^ ((c >> 3) & 3);
        bP0 = Wb + (size_t)(col0 + r) * K_DIM + g * 8;
    }

    // LDS read base byte-offsets (m/n add 1024; swizzle invariant under +16 rows).
    const int rA = wm + (lane & 15);
    const int rB = wn + (lane & 15);
    const int gK = lane >> 4;                        // k-chunk 0..3
    const int aOff = ((rA >> 1) << 7) + ((rA & 1) << 6)
                   + ((gK ^ ((rA >> 1) & 3)) << 4);
    const int bOff = ((rB >> 1) << 7) + ((rB & 1) << 6)
                   + ((gK ^ ((rB >> 1) & 3)) << 4);

    f32x4 acc[4][4] = {};

    auto compute = [&]() {
        bf16x8 av[4], bv[4];
#pragma unroll
        for (int m = 0; m < 4; ++m)
            av[m] = *reinterpret_cast<bf16x8*>(
                reinterpret_cast<char*>(As) + aOff + m * 1024);
#pragma unroll
        for (int n = 0; n < 4; ++n)
            bv[n] = *reinterpret_cast<bf16x8*>(
                reinterpret_cast<char*>(Bs) + bOff + n * 1024);
#pragma unroll
        for (int m = 0; m < 4; ++m)
#pragma unroll
            for (int n = 0; n < 4; ++n)
                acc[m][n] = __builtin_amdgcn_mfma_f32_16x16x32_bf16(
                    av[m], bv[n], acc[m][n], 0, 0, 0);
    };

    // One K-step: stage 24KB (3 loads/thread, literal byte offset T*64),
    // drain+barrier, 16 MFMA/wave, barrier.
#define GSTEP(T)                                                              \
    do {                                                                      \
        __builtin_amdgcn_global_load_lds(                                     \
            (const __attribute__((address_space(1))) void*)aP[0],             \
            (__attribute__((address_space(3))) void*)                         \
                ((char*)As + wave * 1024), 16, (T) * 64, 0);                  \
        __builtin_amdgcn_global_load_lds(                                     \
            (const __attribute__((address_space(1))) void*)aP[1],             \
            (__attribute__((address_space(3))) void*)                         \
                ((char*)As + 8192 + wave * 1024), 16, (T) * 64, 0);           \
        __builtin_amdgcn_global_load_lds(                                     \
            (const __attribute__((address_space(1))) void*)bP0,               \
            (__attribute__((address_space(3))) void*)                         \
                ((char*)Bs + wave * 1024), 16, (T) * 64, 0);                  \
        __syncthreads();                                                      \
        compute();                                                            \
        __syncthreads();                                                      \
    } while (0)

    GSTEP(0); GSTEP(1); GSTEP(2); GSTEP(3);
    GSTEP(4); GSTEP(5); GSTEP(6); GSTEP(7);
#undef GSTEP

    // ---- epilogue: acc IS the logit (W pre-scaled by 30) ----
    // exp(logit-30) = exp2(fma(a, log2e, -30*log2e)): 1 FMA + 1 v_exp.
    // C frag layout: col = lane&15, row = (lane>>4)*4 + reg (verified).
    // 220 zero-pad cols add ~0.4% to S -> loss bias ~4e-3 << 0.22
    // (validated empirically R5/R6/R7/R12).
    const float C1 = 1.44269504088896340f;     // log2(e)
    const float C2 = -43.2808512266689020f;    // -30*log2(e)
#pragma unroll
    for (int m = 0; m < 4; ++m) {
#pragma unroll
        for (int reg = 0; reg < 4; ++reg) {
            int lrow = wm + m * 16 + (lane >> 4) * 4 + reg;
            int grow = row0 + lrow;
            int lab  = lbl[lrow];
            float s = 0.0f, labAcc = 0.0f;
            bool has = false;
#pragma unroll
            for (int n = 0; n < 4; ++n) {
                int gcol = col0 + wn + n * 16 + (lane & 15);
                float a = acc[m][n][reg];
                s += exp2f(fmaf(a, C1, C2));
                bool hit = (gcol == lab);
                labAcc = hit ? a : labAcc;
                has |= hit;
            }
            if (has) labelLogit[grow] = labAcc;   // unique writer per row
#pragma unroll
            for (int off = 1; off < 16; off <<= 1) s += __shfl_xor(s, off, 64);
            if ((lane & 15) == 0) rs[lrow][wc] = s;
        }
    }
    __syncthreads();
    if (tid < BM)
        partial[(size_t)ct * N_ROWS + row0 + tid] = rs[tid][0] + rs[tid][1];
}

// Per-row nll + per-block partial sums (fixed order -> deterministic).
__global__ __launch_bounds__(256) void oim_rownll(
    const float* __restrict__ partial, const float* __restrict__ labelLogit,
    const int* __restrict__ roi, float* __restrict__ blksum)
{
    __shared__ float s1[256], s2[256];
    int tid = threadIdx.x;
    int r = blockIdx.x * 256 + tid;
    float S = 0.0f;
    for (int t = 0; t < CT; ++t) S += partial[(size_t)t * N_ROWS + r];
    float lse = 30.0f + logf(S);
    int lab = roi[r] - 1;
    bool valid = (lab != IGN);
    s1[tid] = valid ? (lse - labelLogit[r]) : 0.0f;
    s2[tid] = valid ? 1.0f : 0.0f;
    __syncthreads();
    for (int o = 128; o > 0; o >>= 1) {
        if (tid < o) { s1[tid] += s1[tid + o]; s2[tid] += s2[tid + o]; }
        __syncthreads();
    }
    if (tid == 0) {
        blksum[blockIdx.x]      = s1[0];
        blksum[32 + blockIdx.x] = s2[0];
    }
}

// Final: one wave reduces the 32 block sums.
__global__ __launch_bounds__(64) void oim_reduce(
    const float* __restrict__ blksum, float* __restrict__ out)
{
    int tid = threadIdx.x;
    float a = (tid < 32) ? blksum[tid]      : 0.0f;
    float b = (tid < 32) ? blksum[32 + tid] : 0.0f;
#pragma unroll
    for (int off = 32; off > 0; off >>= 1) {
        a += __shfl_xor(a, off, 64);
        b += __shfl_xor(b, off, 64);
    }
    if (tid == 0) out[0] = a / fmaxf(b, 1.0f);
}

extern "C" void kernel_launch(void* const* d_in, const int* in_sizes, int n_in,
                              void* d_out, int out_size, void* d_ws, size_t ws_size,
                              hipStream_t stream)
{
    const float* X   = (const float*)d_in[0];
    const int*   roi = (const int*)  d_in[1];
    const float* lut = (const float*)d_in[2];
    const float* cq  = (const float*)d_in[3];
    float* out = (float*)d_out;

    char* ws = (char*)d_ws;
    unsigned short* Xb = (unsigned short*)ws;                  // 8192*256 bf16
    unsigned short* Wb = Xb + (size_t)N_ROWS * K_DIM;          // 10752*256 bf16
    float* partial     = (float*)(Wb + (size_t)NCPAD * K_DIM); // 84*8192 f32
    float* labelLogit  = partial + (size_t)CT * N_ROWS;        // 8192
    float* blksum      = labelLogit + N_ROWS;                  // 64
    size_t need = (size_t)N_ROWS * K_DIM * 2 + (size_t)NCPAD * K_DIM * 2
                + (size_t)CT * N_ROWS * 4 + (size_t)(N_ROWS + 64) * 4;
    if (ws_size < need) return;   // refuse to run rather than corrupt memory

    const int TOT_CHUNKS = ((N_ROWS + NCPAD) * K_DIM) / 8;     // 606208
    oim_convert<<<(TOT_CHUNKS + 255) / 256, 256, 0, stream>>>(X, lut, cq, Xb, Wb);
    oim_gemm<<<NBLK, 512, 0, stream>>>(Xb, Wb, roi, partial, labelLogit);
    oim_rownll<<<N_ROWS / 256, 256, 0, stream>>>(partial, labelLogit, roi, blksum);
    oim_reduce<<<1, 64, 0, stream>>>(blksum, out);
}

// Round 15
// 84.783 us; speedup vs baseline: 6.5414x; 6.5414x over previous
//
#include <hip/hip_runtime.h>
#include <hip/hip_bf16.h>
#include <cstdint>
#include <cstddef>

#define N_ROWS 8192
#define K_DIM  256
#define NP     5532
#define NC     10532
#define NCPAD  10752    // 84*128, zero-padded classes
#define IGN    5554
#define BM     128
#define BN     128
#define BK     32
#define CT     84             // NCPAD / BN
#define NBLK   (CT * 64)      // 5376 blocks, %8==0 -> bijective XCD swizzle
#define CPX    (NBLK / 8)     // 672

using f32x4  = __attribute__((ext_vector_type(4))) float;
using bf16x8 = __attribute__((ext_vector_type(8))) short;

__device__ __forceinline__ unsigned short f2bf(float f) {
    __hip_bfloat16 h = __float2bfloat16(f);
    return __builtin_bit_cast(unsigned short, h);
}

// One-shot f32 -> bf16 conversion of X and W=[lut;cq;zero-pad] (R7-exact).
__global__ __launch_bounds__(256) void oim_convert(
    const float* __restrict__ X, const float* __restrict__ lut,
    const float* __restrict__ cq,
    unsigned short* __restrict__ Xb, unsigned short* __restrict__ Wb)
{
    const int XCH = (N_ROWS * K_DIM) / 8;   // 262144 chunks of 8 elems
    const int WCH = (NCPAD * K_DIM) / 8;    // 344064
    int c = blockIdx.x * 256 + threadIdx.x;
    if (c >= XCH + WCH) return;
    const float* src = nullptr;
    unsigned short* dst;
    if (c < XCH) {
        src = X + (size_t)c * 8;
        dst = Xb + (size_t)c * 8;
    } else {
        int wc  = c - XCH;
        int row = wc >> 5;          // 32 chunks per 256-elem row
        int off = (wc & 31) * 8;
        dst = Wb + (size_t)wc * 8;
        if (row < NP)      src = lut + (size_t)row * K_DIM + off;
        else if (row < NC) src = cq + (size_t)(row - NP) * K_DIM + off;
    }
    ushort4 h0 = {0, 0, 0, 0}, h1 = {0, 0, 0, 0};
    if (src) {
        float4 v0 = *reinterpret_cast<const float4*>(src);
        float4 v1 = *reinterpret_cast<const float4*>(src + 4);
        h0.x = f2bf(v0.x); h0.y = f2bf(v0.y); h0.z = f2bf(v0.z); h0.w = f2bf(v0.w);
        h1.x = f2bf(v1.x); h1.y = f2bf(v1.y); h1.z = f2bf(v1.z); h1.w = f2bf(v1.w);
    }
    *reinterpret_cast<ushort4*>(dst)     = h0;
    *reinterpret_cast<ushort4*>(dst + 4) = h1;
}

// 128x128 bf16 GEMM, BK=32, 18KB LDS, 4 blocks/CU target — R7's proven
// geometry/swizzle/staging, with ONE change: K-step phase order is now
//   {ds_read frags -> __syncthreads -> STAGE(T+1) -> MFMA -> __syncthreads}
// so the single-buffer stage's vmcnt(0) drain (inside the 2nd sync)
// overlaps with the 16 register-only MFMAs in-wave. Safe by construction:
// sync(a) drains every wave's lgkmcnt before any wave's overwrite lands.
// LDS layout (per operand, 128 rows x 32 k): two rows per 128B line,
//   byte(r,g) = (r>>1)*128 + (r&1)*64 + ((g ^ ((r>>1)&3))<<4), g = k/8
// -> ds_read_b128 reads exactly 2-way bank-aliased (free, m136).
// Staged via global_load_lds w=16 (linear dest); source pre-permuted with
// the inverse map r=((c>>3)<<1)|((c>>2)&1), g=(c&3)^((c>>3)&3). (R7-verified)
__global__ __launch_bounds__(256, 4) void oim_gemm(
    const unsigned short* __restrict__ Xb, const unsigned short* __restrict__ Wb,
    const int* __restrict__ roi,
    float* __restrict__ partial, float* __restrict__ labelLogit)
{
    const int bid = blockIdx.x;
    const int L   = (bid & 7) * CPX + (bid >> 3);   // XCD-chunked, bijective
    const int ct  = L >> 6;                          // 0..83 (class tile)
    const int rt  = L & 63;                          // 0..63 (row tile)
    const int row0 = rt * BM;
    const int col0 = ct * BN;
    const int tid  = threadIdx.x;
    const int wave = tid >> 6;
    const int lane = tid & 63;
    const int wm   = (wave >> 1) * 64;
    const int wn   = (wave & 1) * 64;

    __shared__ __align__(16) unsigned short As[BM * BK];   // 8 KB
    __shared__ __align__(16) unsigned short Bs[BN * BK];   // 8 KB
    __shared__ int   lbl[BM];
    __shared__ float rs[BM][2];

    if (tid < BM) lbl[tid] = roi[row0 + tid] - 1;

    // Staging source pointers (pre-permuted), one per 256-chunk group.
    const unsigned short* aP[2];
    const unsigned short* bP[2];
#pragma unroll
    for (int i = 0; i < 2; ++i) {
        int c = i * 256 + tid;
        int r = ((c >> 3) << 1) | ((c >> 2) & 1);
        int g = (c & 3) ^ ((c >> 3) & 3);
        aP[i] = Xb + (size_t)(row0 + r) * K_DIM + g * 8;
        bP[i] = Wb + (size_t)(col0 + r) * K_DIM + g * 8;
    }

    // LDS read base byte-offsets (m/n add 1024; swizzle invariant under +16 rows).
    const int rA = wm + (lane & 15);
    const int rB = wn + (lane & 15);
    const int gK = lane >> 4;                        // k-chunk 0..3
    const int aOff = ((rA >> 1) << 7) + ((rA & 1) << 6)
                   + ((gK ^ ((rA >> 1) & 3)) << 4);
    const int bOff = ((rB >> 1) << 7) + ((rB & 1) << 6)
                   + ((gK ^ ((rB >> 1) & 3)) << 4);

    f32x4 acc[4][4] = {};
    bf16x8 av[4], bv[4];

    auto ldsread = [&]() {
#pragma unroll
        for (int m = 0; m < 4; ++m)
            av[m] = *reinterpret_cast<bf16x8*>(
                reinterpret_cast<char*>(As) + aOff + m * 1024);
#pragma unroll
        for (int n = 0; n < 4; ++n)
            bv[n] = *reinterpret_cast<bf16x8*>(
                reinterpret_cast<char*>(Bs) + bOff + n * 1024);
    };
    auto mfma = [&]() {
#pragma unroll
        for (int m = 0; m < 4; ++m)
#pragma unroll
            for (int n = 0; n < 4; ++n)
                acc[m][n] = __builtin_amdgcn_mfma_f32_16x16x32_bf16(
                    av[m], bv[n], acc[m][n], 0, 0, 0);
    };

#define STAGE(T)                                                              \
    do {                                                                      \
        __builtin_amdgcn_global_load_lds(                                     \
            (const __attribute__((address_space(1))) void*)aP[0],             \
            (__attribute__((address_space(3))) void*)                         \
                ((char*)As + wave * 1024), 16, (T) * 64, 0);                  \
        __builtin_amdgcn_global_load_lds(                                     \
            (const __attribute__((address_space(1))) void*)aP[1],             \
            (__attribute__((address_space(3))) void*)                         \
                ((char*)As + 4096 + wave * 1024), 16, (T) * 64, 0);           \
        __builtin_amdgcn_global_load_lds(                                     \
            (const __attribute__((address_space(1))) void*)bP[0],             \
            (__attribute__((address_space(3))) void*)                         \
                ((char*)Bs + wave * 1024), 16, (T) * 64, 0);                  \
        __builtin_amdgcn_global_load_lds(                                     \
            (const __attribute__((address_space(1))) void*)bP[1],             \
            (__attribute__((address_space(3))) void*)                         \
                ((char*)Bs + 4096 + wave * 1024), 16, (T) * 64, 0);           \
    } while (0)

    // Pipelined K-steps: reads complete at sync(a); next stage issues and
    // its drain (inside sync(b)) overlaps the register-only MFMAs.
#define ITER(T)                                                               \
    do {                                                                      \
        ldsread();                                                            \
        __syncthreads();   /* (a) all waves' frags in regs              */    \
        STAGE((T) + 1);    /* overwrite single buffer, latency starts   */    \
        mfma();            /* overlaps stage latency                    */    \
        __syncthreads();   /* (b) vmcnt(0) drain: buffer ready for T+1  */    \
    } while (0)

    STAGE(0);
    __syncthreads();
    ITER(0); ITER(1); ITER(2); ITER(3); ITER(4); ITER(5); ITER(6);
    ldsread();             // tile 7: compiler inserts lgkm waits before use
    mfma();
#undef ITER
#undef STAGE

    // ---- epilogue (R7-exact): logits*30, exp(logit-30) row-sums, label ----
    // C frag layout: col = lane&15, row = (lane>>4)*4 + reg (verified).
    // 220 zero-pad cols add ~0.4% to S -> loss bias ~4e-3 << 0.22
    // (validated empirically R5/R6/R7/R12).
#pragma unroll
    for (int m = 0; m < 4; ++m) {
#pragma unroll
        for (int reg = 0; reg < 4; ++reg) {
            int lrow = wm + m * 16 + (lane >> 4) * 4 + reg;
            int grow = row0 + lrow;
            int lab  = lbl[lrow];
            float s = 0.0f;
#pragma unroll
            for (int n = 0; n < 4; ++n) {
                int gcol = col0 + wn + n * 16 + (lane & 15);
                float logit = acc[m][n][reg] * 30.0f;
                s += __expf(logit - 30.0f);
                if (gcol == lab) labelLogit[grow] = logit;  // unique writer
            }
#pragma unroll
            for (int off = 1; off < 16; off <<= 1) s += __shfl_xor(s, off, 64);
            if ((lane & 15) == 0) rs[lrow][wave & 1] = s;
        }
    }
    __syncthreads();
    if (tid < BM)
        partial[(size_t)ct * N_ROWS + row0 + tid] = rs[tid][0] + rs[tid][1];
}

// Per-row nll + per-block partial sums (fixed order -> deterministic).
__global__ __launch_bounds__(256) void oim_rownll(
    const float* __restrict__ partial, const float* __restrict__ labelLogit,
    const int* __restrict__ roi, float* __restrict__ blksum)
{
    __shared__ float s1[256], s2[256];
    int tid = threadIdx.x;
    int r = blockIdx.x * 256 + tid;
    float S = 0.0f;
    for (int t = 0; t < CT; ++t) S += partial[(size_t)t * N_ROWS + r];
    float lse = 30.0f + logf(S);
    int lab = roi[r] - 1;
    bool valid = (lab != IGN);
    s1[tid] = valid ? (lse - labelLogit[r]) : 0.0f;
    s2[tid] = valid ? 1.0f : 0.0f;
    __syncthreads();
    for (int o = 128; o > 0; o >>= 1) {
        if (tid < o) { s1[tid] += s1[tid + o]; s2[tid] += s2[tid + o]; }
        __syncthreads();
    }
    if (tid == 0) {
        blksum[blockIdx.x]      = s1[0];
        blksum[32 + blockIdx.x] = s2[0];
    }
}

// Final: one wave reduces the 32 block sums.
__global__ __launch_bounds__(64) void oim_reduce(
    const float* __restrict__ blksum, float* __restrict__ out)
{
    int tid = threadIdx.x;
    float a = (tid < 32) ? blksum[tid]      : 0.0f;
    float b = (tid < 32) ? blksum[32 + tid] : 0.0f;
#pragma unroll
    for (int off = 32; off > 0; off >>= 1) {
        a += __shfl_xor(a, off, 64);
        b += __shfl_xor(b, off, 64);
    }
    if (tid == 0) out[0] = a / fmaxf(b, 1.0f);
}

extern "C" void kernel_launch(void* const* d_in, const int* in_sizes, int n_in,
                              void* d_out, int out_size, void* d_ws, size_t ws_size,
                              hipStream_t stream)
{
    const float* X   = (const float*)d_in[0];
    const int*   roi = (const int*)  d_in[1];
    const float* lut = (const float*)d_in[2];
    const float* cq  = (const float*)d_in[3];
    float* out = (float*)d_out;

    char* ws = (char*)d_ws;
    unsigned short* Xb = (unsigned short*)ws;                  // 8192*256 bf16
    unsigned short* Wb = Xb + (size_t)N_ROWS * K_DIM;          // 10752*256 bf16
    float* partial     = (float*)(Wb + (size_t)NCPAD * K_DIM); // 84*8192 f32
    float* labelLogit  = partial + (size_t)CT * N_ROWS;        // 8192
    float* blksum      = labelLogit + N_ROWS;                  // 64
    size_t need = (size_t)N_ROWS * K_DIM * 2 + (size_t)NCPAD * K_DIM * 2
                + (size_t)CT * N_ROWS * 4 + (size_t)(N_ROWS + 64) * 4;
    if (ws_size < need) return;   // refuse to run rather than corrupt memory

    const int TOT_CHUNKS = ((N_ROWS + NCPAD) * K_DIM) / 8;     // 606208
    oim_convert<<<(TOT_CHUNKS + 255) / 256, 256, 0, stream>>>(X, lut, cq, Xb, Wb);
    oim_gemm<<<NBLK, 256, 0, stream>>>(Xb, Wb, roi, partial, labelLogit);
    oim_rownll<<<N_ROWS / 256, 256, 0, stream>>>(partial, labelLogit, roi, blksum);
    oim_reduce<<<1, 64, 0, stream>>>(blksum, out);
}